// Round 8
// baseline (163.402 us; speedup 1.0000x reference)
//
#include <hip/hip_runtime.h>

#define TH 8
#define W_ 1024
#define H_ 1024

struct Raw {
    float4 cb, cd, cz;                 // center cols c..c+3
    float2 lb, ld, lz, rb, rd, rz;     // side cols (c-2,c-1) and (c+4,c+5)
};

__device__ __forceinline__ Raw load_raw(int gy,
    const float* __restrict__ bB, const float* __restrict__ dB,
    const float* __restrict__ zB, int c, int colL2, int colR2)
{
    Raw r;
    if ((unsigned)gy < (unsigned)H_) {   // block-uniform
        const size_t ro = (size_t)gy * W_;
        r.cb = *(const float4*)(bB + ro + c);
        r.cd = *(const float4*)(dB + ro + c);
        r.cz = *(const float4*)(zB + ro + c);
        r.lb = *(const float2*)(bB + ro + colL2);
        r.ld = *(const float2*)(dB + ro + colL2);
        r.lz = *(const float2*)(zB + ro + colL2);
        r.rb = *(const float2*)(bB + ro + colR2);
        r.rd = *(const float2*)(dB + ro + colR2);
        r.rz = *(const float2*)(zB + ro + colR2);
    } else {
        r.cb = r.cd = r.cz = make_float4(0.f, 0.f, 0.f, 0.f);
        r.lb = r.ld = r.lz = make_float2(0.f, 0.f);
        r.rb = r.rd = r.rz = make_float2(0.f, 0.f);
    }
    return r;
}

__device__ __forceinline__ float wexp1(float zp, float iz, float kd, float kspat) {
    const float u = fmaf(zp, iz, -1.0f);
    return __builtin_amdgcn_exp2f(fmaf(u * kd, u, kspat));
}

// 5-tap depth-guided blur of (b,d) around center; taps m2,m1,[c],p1,p2
__device__ __forceinline__ void blur5(
    float zm2, float zm1, float zc, float zp1, float zp2,
    float bm2, float bm1, float bc, float bp1, float bp2,
    float dm2, float dm1, float dc, float dp1, float dp2,
    float kd, float ks1, float ks4,
    float& ob, float& od)
{
    const float iz = __builtin_amdgcn_rcpf(zc);
    const float w0 = wexp1(zm2, iz, kd, ks4);
    const float w1 = wexp1(zm1, iz, kd, ks1);
    const float w3 = wexp1(zp1, iz, kd, ks1);
    const float w4 = wexp1(zp2, iz, kd, ks4);
    const float wr = __builtin_amdgcn_rcpf(1.0f + w0 + w1 + w3 + w4);
    ob = fmaf(w0, bm2, fmaf(w1, bm1, fmaf(w3, bp1, fmaf(w4, bp2, bc)))) * wr;
    od = fmaf(w0, dm2, fmaf(w1, dm1, fmaf(w3, dp1, fmaf(w4, dp2, dc)))) * wr;
}

__device__ __forceinline__ float blend1(float bc, float dc, float bm, float dm,
                                        float de, float dke, float ce) {
    const float devb = __builtin_amdgcn_exp2f(
        de * __builtin_amdgcn_logf(fmaxf(fabsf(bc - bm), 1e-8f))) * ce;
    const float devd = fmaxf(__builtin_amdgcn_exp2f(
        de * __builtin_amdgcn_logf(fmaxf(fabsf(dc - dm), 1e-8f))), dke);
    const float wr = __builtin_amdgcn_rcpf(devb + devd);
    return fmaf(devd, bc, devb * dc) * wr;
}

// horizontal blur of raw row (loaded in a previous step) into a pipeline slot
__device__ __forceinline__ void hblur(
    int gy, const Raw& r, bool eL, bool eR,
    float kd, float ks1, float ks4,
    float4& sb, float4& sd, float4& sz)
{
    if ((unsigned)gy < (unsigned)H_) {   // block-uniform
        float2 lz = r.lz, rz = r.rz;
        // image-edge taps: poison depth -> |t| huge -> kd*t^2 = -inf -> w = 0
        // (matches the reference's zero-padding exactly)
        if (eL) { lz.x = 1e18f; lz.y = 1e18f; }
        if (eR) { rz.x = 1e18f; rz.y = 1e18f; }
        blur5(lz.x,   lz.y,   r.cz.x, r.cz.y, r.cz.z,
              r.lb.x, r.lb.y, r.cb.x, r.cb.y, r.cb.z,
              r.ld.x, r.ld.y, r.cd.x, r.cd.y, r.cd.z,
              kd, ks1, ks4, sb.x, sd.x);
        blur5(lz.y,   r.cz.x, r.cz.y, r.cz.z, r.cz.w,
              r.lb.y, r.cb.x, r.cb.y, r.cb.z, r.cb.w,
              r.ld.y, r.cd.x, r.cd.y, r.cd.z, r.cd.w,
              kd, ks1, ks4, sb.y, sd.y);
        blur5(r.cz.x, r.cz.y, r.cz.z, r.cz.w, rz.x,
              r.cb.x, r.cb.y, r.cb.z, r.cb.w, r.rb.x,
              r.cd.x, r.cd.y, r.cd.z, r.cd.w, r.rd.x,
              kd, ks1, ks4, sb.z, sd.z);
        blur5(r.cz.y, r.cz.z, r.cz.w, rz.x,   rz.y,
              r.cb.y, r.cb.z, r.cb.w, r.rb.x, r.rb.y,
              r.cd.y, r.cd.z, r.cd.w, r.rd.x, r.rd.y,
              kd, ks1, ks4, sb.w, sd.w);
        sz = r.cz;
    } else {
        // zero-pad row: z=0 -> vertical tap weight underflows to exact 0
        sb = make_float4(0.f, 0.f, 0.f, 0.f);
        sd = make_float4(0.f, 0.f, 0.f, 0.f);
        sz = make_float4(0.f, 0.f, 0.f, 0.f);
    }
}

// One steady-state step I (output row y0+I-4):
//   1. prefetch raw row y0+I-1 into RNXT (used by NEXT step's hblur)
//   2. issue blend re-reads for the output row (independent, L1-hot)
//   3. hblur RCUR (row y0+I-2, loaded last step) into slot S
//   4. vertical blur slots S0..S4 + blend + store
#define STEP(RCUR, RNXT, PRE, S, S0, S1, S2, S3, S4, I)                       \
  {                                                                           \
    if (PRE) RNXT = load_raw(y0 + (I) - 1, bB, dB, zB, c, colL2, colR2);      \
    const size_t oo = (size_t)(y0 + (I) - 4) * W_ + c;                        \
    const float4 rb4 = *(const float4*)(bB + oo);                             \
    const float4 rd4 = *(const float4*)(dB + oo);                             \
    hblur(y0 + (I) - 2, RCUR, eL, eR, kd, ks1, ks4, pb[S], pd[S], pz[S]);     \
    float4 bm, dm;                                                            \
    blur5(pz[S0].x, pz[S1].x, pz[S2].x, pz[S3].x, pz[S4].x,                   \
          pb[S0].x, pb[S1].x, pb[S2].x, pb[S3].x, pb[S4].x,                   \
          pd[S0].x, pd[S1].x, pd[S2].x, pd[S3].x, pd[S4].x,                   \
          kd, ks1, ks4, bm.x, dm.x);                                          \
    blur5(pz[S0].y, pz[S1].y, pz[S2].y, pz[S3].y, pz[S4].y,                   \
          pb[S0].y, pb[S1].y, pb[S2].y, pb[S3].y, pb[S4].y,                   \
          pd[S0].y, pd[S1].y, pd[S2].y, pd[S3].y, pd[S4].y,                   \
          kd, ks1, ks4, bm.y, dm.y);                                          \
    blur5(pz[S0].z, pz[S1].z, pz[S2].z, pz[S3].z, pz[S4].z,                   \
          pb[S0].z, pb[S1].z, pb[S2].z, pb[S3].z, pb[S4].z,                   \
          pd[S0].z, pd[S1].z, pd[S2].z, pd[S3].z, pd[S4].z,                   \
          kd, ks1, ks4, bm.z, dm.z);                                          \
    blur5(pz[S0].w, pz[S1].w, pz[S2].w, pz[S3].w, pz[S4].w,                   \
          pb[S0].w, pb[S1].w, pb[S2].w, pb[S3].w, pb[S4].w,                   \
          pd[S0].w, pd[S1].w, pd[S2].w, pd[S3].w, pd[S4].w,                   \
          kd, ks1, ks4, bm.w, dm.w);                                          \
    float4 res;                                                               \
    res.x = blend1(rb4.x, rd4.x, bm.x, dm.x, de, dke, ce);                    \
    res.y = blend1(rb4.y, rd4.y, bm.y, dm.y, de, dke, ce);                    \
    res.z = blend1(rb4.z, rd4.z, bm.z, dm.z, de, dke, ce);                    \
    res.w = blend1(rb4.w, rd4.w, bm.w, dm.w, de, dke, ce);                    \
    *(float4*)(outB + oo) = res;                                              \
  }

__global__ __launch_bounds__(256, 4)
void bilateral_fused(const float* __restrict__ bright,
                     const float* __restrict__ dark,
                     const float* __restrict__ depths,
                     const float* __restrict__ p_dv,
                     const float* __restrict__ p_sv,
                     const float* __restrict__ p_de,
                     const float* __restrict__ p_deps,
                     const float* __restrict__ p_ce,
                     float* __restrict__ out)
{
    const float LOG2E = 1.44269504088896340736f;
    const float kd  = -LOG2E / (2.0f * p_dv[0]);   // ~ -1803
    const float ks  = -LOG2E / (2.0f * p_sv[0]);
    const float de  = p_de[0];
    const float dke = p_deps[0];
    const float ce  = p_ce[0];
    const float ks1 = ks;
    const float ks4 = 4.0f * ks;

    const int t  = threadIdx.x;           // 0..255
    const int c  = 4 * t;                 // cols c..c+3
    const int y0 = blockIdx.y * TH;

    const size_t plane = (size_t)H_ * W_;
    const float* bB = bright + (size_t)blockIdx.z * plane;
    const float* dB = dark   + (size_t)blockIdx.z * plane;
    const float* zB = depths + (size_t)blockIdx.z * plane;
    float*     outB = out    + (size_t)blockIdx.z * plane;

    const int  colL2 = max(c - 2, 0);        // float2 [c-2,c-1], 8B aligned
    const int  colR2 = min(c + 4, W_ - 2);   // float2 [c+4,c+5]
    const bool eL = (c == 0);
    const bool eR = (c + 4 >= W_);

    // 5-deep register pipeline: horizontally-blurred (b,d) + center depths
    float4 pb[5], pd[5], pz[5];
    Raw rawA, rawB;

    // warm-up: stage rows y0-2 .. y0+1 into slots 0..3, prefetch distance 1
    rawA = load_raw(y0 - 2, bB, dB, zB, c, colL2, colR2);
    rawB = load_raw(y0 - 1, bB, dB, zB, c, colL2, colR2);
    hblur(y0 - 2, rawA, eL, eR, kd, ks1, ks4, pb[0], pd[0], pz[0]);
    rawA = load_raw(y0 + 0, bB, dB, zB, c, colL2, colR2);
    hblur(y0 - 1, rawB, eL, eR, kd, ks1, ks4, pb[1], pd[1], pz[1]);
    rawB = load_raw(y0 + 1, bB, dB, zB, c, colL2, colR2);
    hblur(y0 + 0, rawA, eL, eR, kd, ks1, ks4, pb[2], pd[2], pz[2]);
    rawA = load_raw(y0 + 2, bB, dB, zB, c, colL2, colR2);
    hblur(y0 + 1, rawB, eL, eR, kd, ks1, ks4, pb[3], pd[3], pz[3]);

    // steady state: steps i = 4..11 (stage rows y0+2..y0+9, out rows y0+0..7)
    STEP(rawA, rawB, true,  4, 0, 1, 2, 3, 4,  4)
    STEP(rawB, rawA, true,  0, 1, 2, 3, 4, 0,  5)
    STEP(rawA, rawB, true,  1, 2, 3, 4, 0, 1,  6)
    STEP(rawB, rawA, true,  2, 3, 4, 0, 1, 2,  7)
    STEP(rawA, rawB, true,  3, 4, 0, 1, 2, 3,  8)
    STEP(rawB, rawA, true,  4, 0, 1, 2, 3, 4,  9)
    STEP(rawA, rawB, true,  0, 1, 2, 3, 4, 0, 10)
    STEP(rawB, rawA, false, 1, 2, 3, 4, 0, 1, 11)
}

extern "C" void kernel_launch(void* const* d_in, const int* in_sizes, int n_in,
                              void* d_out, int out_size, void* d_ws, size_t ws_size,
                              hipStream_t stream)
{
    const float* bright = (const float*)d_in[0];
    const float* dark   = (const float*)d_in[1];
    const float* depths = (const float*)d_in[2];
    const float* p_dv   = (const float*)d_in[3];
    const float* p_sv   = (const float*)d_in[4];
    const float* p_de   = (const float*)d_in[5];
    const float* p_deps = (const float*)d_in[6];
    const float* p_ce   = (const float*)d_in[7];
    float* out = (float*)d_out;

    const int B = in_sizes[0] / (H_ * W_);

    dim3 grid(1, H_ / TH, B);
    dim3 block(256);
    bilateral_fused<<<grid, block, 0, stream>>>(bright, dark, depths,
                                                p_dv, p_sv, p_de, p_deps, p_ce,
                                                out);
}